// Round 1
// 218.598 us; speedup vs baseline: 1.0102x; 1.0102x over previous
//
#include <hip/hip_runtime.h>
#include <cstdint>
#include <cstddef>

typedef __bf16 bf16;
typedef __bf16 bf16x8 __attribute__((ext_vector_type(8)));
typedef float f32x4 __attribute__((ext_vector_type(4)));

#define DEVI static __device__ __forceinline__

// pack two f32 -> two bf16 (RTNE) in one uint
DEVI unsigned int cvt_pk_bf16(float lo, float hi) {
  unsigned int bl = __float_as_uint(lo);
  bl += 0x7fffu + ((bl >> 16) & 1u);
  unsigned int bh = __float_as_uint(hi);
  bh += 0x7fffu + ((bh >> 16) & 1u);
  return (bl >> 16) | (bh & 0xffff0000u);
}
DEVI float bf_lo(unsigned int u) { return __uint_as_float(u << 16); }
DEVI float bf_hi(unsigned int u) { return __uint_as_float(u & 0xffff0000u); }

// async global->LDS, 16B per lane; LDS dest = wave-uniform base + lane*16
DEVI void gload16(const bf16* g, bf16* l) {
  __builtin_amdgcn_global_load_lds(
      (const __attribute__((address_space(1))) unsigned int*)g,
      (__attribute__((address_space(3))) unsigned int*)l, 16, 0, 0);
}

// ---------------------------------------------------------------------------
// W transpose prepass: W (1024x1024 f32, [k][n]) -> Wt (bf16 [n][k]).
// ---------------------------------------------------------------------------
__global__ __launch_bounds__(256) void wtr_k(
    const float* __restrict__ Wq, const float* __restrict__ Wk,
    const float* __restrict__ Wv, const float* __restrict__ Wo,
    bf16* __restrict__ Wt)
{
  const int z = blockIdx.z;
  const float* W = (z == 0) ? Wq : (z == 1) ? Wk : (z == 2) ? Wv : Wo;
  bf16* out = Wt + ((size_t)z << 20);
  const int n0 = blockIdx.x * 64, k0 = blockIdx.y * 64;
  __shared__ bf16 Ts[64 * 72];
  const int tid = threadIdx.x;
  #pragma unroll
  for (int i = 0; i < 4; ++i) {
    int t = tid + i * 256;
    int kr = t >> 4, nc = t & 15;
    float4 v = *(const float4*)(W + (size_t)(k0 + kr) * 1024 + n0 + nc * 4);
    Ts[(nc * 4 + 0) * 72 + kr] = (bf16)v.x;
    Ts[(nc * 4 + 1) * 72 + kr] = (bf16)v.y;
    Ts[(nc * 4 + 2) * 72 + kr] = (bf16)v.z;
    Ts[(nc * 4 + 3) * 72 + kr] = (bf16)v.w;
  }
  __syncthreads();
  const int n = tid >> 2, kc = tid & 3;
  *(uint4*)(out + (size_t)(n0 + n) * 1024 + k0 + kc * 16) =
      *(const uint4*)(&Ts[n * 72 + kc * 16]);
  *(uint4*)(out + (size_t)(n0 + n) * 1024 + k0 + kc * 16 + 8) =
      *(const uint4*)(&Ts[n * 72 + kc * 16 + 8]);
}

// ---------------------------------------------------------------------------
// A prepass: Q,K,V f32 -> bf16 (RTNE), row-major, 8 elems/thread.
// ---------------------------------------------------------------------------
__global__ __launch_bounds__(256) void a2bf_k(
    const float* __restrict__ Q, const float* __restrict__ K,
    const float* __restrict__ V, bf16* __restrict__ Ab)
{
  const int z = blockIdx.y;
  const float* A = (z == 0) ? Q : (z == 1) ? K : V;
  bf16* o = Ab + ((size_t)z << 21);
  const int idx = blockIdx.x * 256 + threadIdx.x;
  const float4 v0 = *(const float4*)(A + (size_t)idx * 8);
  const float4 v1 = *(const float4*)(A + (size_t)idx * 8 + 4);
  uint4 u;
  u.x = cvt_pk_bf16(v0.x, v0.y);
  u.y = cvt_pk_bf16(v0.z, v0.w);
  u.z = cvt_pk_bf16(v1.x, v1.y);
  u.w = cvt_pk_bf16(v1.z, v1.w);
  *(uint4*)(o + (size_t)idx * 8) = u;
}

// ---------------------------------------------------------------------------
// Fused projection GEMM, bf16 A (prepass), 128x64 tile, BK=32.
// global_load_lds both operands; swizzled GLOBAL source addresses so the
// linear LDS layout reads conflict-free with chunk swizzle q4^((n16>>1)&3).
// 2-phase double-buffered LDS, one barrier per K-step.
// grid (256,1,3): mtile = bid&15 fastest -> blocks sharing an A-stripe land
// on one XCD. z=0 Q->qh, z=1 K->kh (B,H,S,HD); z=2: V -> V2 PV-B-frag order
// (direct coalesced 8B stores, no LDS transpose).
// ---------------------------------------------------------------------------
__global__ __launch_bounds__(256) void proj_gemm_k(
    const bf16* __restrict__ Ab, const bf16* __restrict__ Wt,
    const float* __restrict__ bq, const float* __restrict__ bk,
    const float* __restrict__ bv, bf16* __restrict__ outbase)
{
  const int z = blockIdx.z;
  const bf16* A  = Ab + ((size_t)z << 21);
  const bf16* Bt = Wt + ((size_t)z << 20);
  const float* bias = (z == 0) ? bq : (z == 1) ? bk : bv;
  bf16* outb = outbase + ((size_t)z << 21);

  __shared__ __align__(16) bf16 As[2][4096];   // [128][32] per buffer
  __shared__ __align__(16) bf16 Bs[2][2048];   // [64][32]  per buffer

  const int tid = threadIdx.x, lane = tid & 63, wid = tid >> 6;
  const int q4 = lane >> 4, n16 = lane & 15;
  const int wm = wid >> 1, wn = wid & 1;
  const int bid = blockIdx.x;
  const int m0 = (bid & 15) * 128, n0 = (bid >> 4) * 64;   // m fastest: XCD reuse

  // staging chunk -> swizzled global k-chunk: ksw = (c&3) ^ ((c>>3)&3)
  const int cA0 = wid * 64 + lane, cA1 = cA0 + 256;
  const bf16* gA0 = A + (size_t)(m0 + (cA0 >> 2)) * 1024 + (((cA0 & 3) ^ ((cA0 >> 3) & 3)) << 3);
  const bf16* gA1 = A + (size_t)(m0 + (cA1 >> 2)) * 1024 + (((cA1 & 3) ^ ((cA1 >> 3) & 3)) << 3);
  const bf16* gB  = Bt + (size_t)(n0 + (cA0 >> 2)) * 1024 + (((cA0 & 3) ^ ((cA0 >> 3) & 3)) << 3);
  const int qsw = (q4 ^ ((n16 >> 1) & 3)) << 4;   // swizzled k-chunk byte offset

  f32x4 acc[4][2] = {};

  // prologue: stage tile 0 -> buf 0
  gload16(gA0, &As[0][wid * 512]);
  gload16(gA1, &As[0][2048 + wid * 512]);
  gload16(gB,  &Bs[0][wid * 512]);
  __syncthreads();

  int cur = 0;
  for (int kb = 0; kb < 32; ++kb) {
    if (kb < 31) {
      const int kc = (kb + 1) * 32;
      gload16(gA0 + kc, &As[cur ^ 1][wid * 512]);
      gload16(gA1 + kc, &As[cur ^ 1][2048 + wid * 512]);
      gload16(gB + kc,  &Bs[cur ^ 1][wid * 512]);
    }
    const char* ab = (const char*)&As[cur][0];
    const char* bb = (const char*)&Bs[cur][0];
    bf16x8 af[4], bfv[2];
    #pragma unroll
    for (int rt = 0; rt < 4; ++rt)
      af[rt] = *(const bf16x8*)(ab + (wm * 64 + rt * 16 + n16) * 64 + qsw);
    #pragma unroll
    for (int ct = 0; ct < 2; ++ct)
      bfv[ct] = *(const bf16x8*)(bb + (wn * 32 + ct * 16 + n16) * 64 + qsw);
    #pragma unroll
    for (int rt = 0; rt < 4; ++rt)
      #pragma unroll
      for (int ct = 0; ct < 2; ++ct)
        acc[rt][ct] = __builtin_amdgcn_mfma_f32_16x16x32_bf16(af[rt], bfv[ct], acc[rt][ct], 0, 0, 0);
    __syncthreads();
    cur ^= 1;
  }

  if (z < 2) {   // (B,H,S,HD)
    const int h = n0 >> 6;
    #pragma unroll
    for (int ct = 0; ct < 2; ++ct) {
      const int dl = wn * 32 + ct * 16 + n16;
      const float bvl = bias[n0 + dl];
      #pragma unroll
      for (int rt = 0; rt < 4; ++rt) {
        #pragma unroll
        for (int r = 0; r < 4; ++r) {
          int row = m0 + wm * 64 + rt * 16 + q4 * 4 + r;
          int b2 = row >> 10, s = row & 1023;
          outb[((size_t)((b2 * 16 + h) * 1024 + s) << 6) + dl] =
              (bf16)(acc[rt][ct][r] + bvl);
        }
      }
    }
  } else {       // V2 fragment layout, direct coalesced 8B stores
    const int b2 = m0 >> 10, kt0 = (m0 & 1023) >> 6, hh = n0 >> 6;
    bf16* vout = outb + ((size_t)(b2 * 16 + hh) << 16) + (size_t)(kt0 + wm) * 4096;
    #pragma unroll
    for (int rt = 0; rt < 4; ++rt) {
      const int kk = rt >> 1;
      const int q4c = (rt & 1) * 2 + (q4 >> 1);
      const int jo = (q4 & 1) * 4;
      #pragma unroll
      for (int ct = 0; ct < 2; ++ct) {
        const int cl = wn * 32 + ct * 16 + n16;
        const float bvl = bias[n0 + cl];
        unsigned int p0 = cvt_pk_bf16(acc[rt][ct][0] + bvl, acc[rt][ct][1] + bvl);
        unsigned int p1 = cvt_pk_bf16(acc[rt][ct][2] + bvl, acc[rt][ct][3] + bvl);
        *(uint2*)(vout + kk * 2048 + (wn * 2 + ct) * 512 + (q4c * 16 + n16) * 8 + jo) =
            make_uint2(p0, p1);
      }
    }
  }
}

// ---------------------------------------------------------------------------
// Output GEMM: d_out = oat(2048x1024 bf16) @ WoT + bo, f32 out.
// Same gload_lds + source-swizzle + 2-phase structure, 64x64 tile (512 blocks
// = 2/CU), grid XCD-aware decode (m fastest).
// ---------------------------------------------------------------------------
__global__ __launch_bounds__(256) void out_gemm_k(
    const bf16* __restrict__ Ab, const bf16* __restrict__ Bt,
    const float* __restrict__ bias, float* __restrict__ outf)
{
  __shared__ __align__(16) bf16 As[2][2048];
  __shared__ __align__(16) bf16 Bs[2][2048];
  const int tid = threadIdx.x, lane = tid & 63, wid = tid >> 6;
  const int q4 = lane >> 4, n16 = lane & 15;
  const int wm = wid >> 1, wn = wid & 1;
  const int bid = blockIdx.x;
  const int m0 = (bid & 31) * 64, n0 = (bid >> 5) * 64;   // XCD swizzle
  const int c = wid * 64 + lane;
  const bf16* gA = Ab + (size_t)(m0 + (c >> 2)) * 1024 + (((c & 3) ^ ((c >> 3) & 3)) << 3);
  const bf16* gB = Bt + (size_t)(n0 + (c >> 2)) * 1024 + (((c & 3) ^ ((c >> 3) & 3)) << 3);
  const int qsw = (q4 ^ ((n16 >> 1) & 3)) << 4;
  f32x4 acc[2][2] = {};

  gload16(gA, &As[0][wid * 512]);
  gload16(gB, &Bs[0][wid * 512]);
  __syncthreads();

  int cur = 0;
  for (int kb = 0; kb < 32; ++kb) {
    if (kb < 31) {
      const int kc = (kb + 1) * 32;
      gload16(gA + kc, &As[cur ^ 1][wid * 512]);
      gload16(gB + kc, &Bs[cur ^ 1][wid * 512]);
    }
    const char* ab = (const char*)&As[cur][0];
    const char* bb = (const char*)&Bs[cur][0];
    bf16x8 af[2], bfv[2];
    #pragma unroll
    for (int rt = 0; rt < 2; ++rt)
      af[rt] = *(const bf16x8*)(ab + (wm * 32 + rt * 16 + n16) * 64 + qsw);
    #pragma unroll
    for (int ct = 0; ct < 2; ++ct)
      bfv[ct] = *(const bf16x8*)(bb + (wn * 32 + ct * 16 + n16) * 64 + qsw);
    #pragma unroll
    for (int rt = 0; rt < 2; ++rt)
      #pragma unroll
      for (int ct = 0; ct < 2; ++ct)
        acc[rt][ct] = __builtin_amdgcn_mfma_f32_16x16x32_bf16(af[rt], bfv[ct], acc[rt][ct], 0, 0, 0);
    __syncthreads();
    cur ^= 1;
  }
  #pragma unroll
  for (int ct = 0; ct < 2; ++ct) {
    int col = n0 + wn * 32 + ct * 16 + n16;
    float bvl = bias[col];
    #pragma unroll
    for (int rt = 0; rt < 2; ++rt)
      #pragma unroll
      for (int r = 0; r < 4; ++r) {
        int row = m0 + wm * 32 + rt * 16 + q4 * 4 + r;
        outf[(size_t)row * 1024 + col] = acc[rt][ct][r] + bvl;
      }
  }
}

// ---------------------------------------------------------------------------
// per-(b,h,ktile) column sums of v (V2 fragment layout) + suffix scan
// ---------------------------------------------------------------------------
__global__ void vtile_sum_k(const bf16* __restrict__ V2, float* __restrict__ Tsum)
{
  int kt = blockIdx.x, h = blockIdx.y, b = blockIdx.z, d = threadIdx.x;
  int ctt = d >> 4, n16c = d & 15;
  const bf16* p = V2 + ((size_t)(b * 16 + h) << 16) + kt * 4096 + ctt * 512 + n16c * 8;
  float s = 0.f;
  #pragma unroll
  for (int kk = 0; kk < 2; ++kk)
    #pragma unroll
    for (int q4i = 0; q4i < 4; ++q4i)
      #pragma unroll
      for (int j = 0; j < 8; ++j)
        s += (float)p[kk * 2048 + q4i * 128 + j];
  Tsum[((b * 16 + h) * 16 + kt) * 64 + d] = s;
}

__global__ void vtail_k(const float* __restrict__ Tsum, float* __restrict__ Vtail)
{
  int h = blockIdx.x, b = blockIdx.y, d = threadIdx.x;
  float c = 0.f;
  Vtail[((b * 16 + h) * 17 + 16) * 64 + d] = 0.f;
  for (int kt = 15; kt >= 0; --kt) {
    c += Tsum[((b * 16 + h) * 16 + kt) * 64 + d];
    Vtail[((b * 16 + h) * 17 + kt) * 64 + d] = c;
  }
}

// ---------------------------------------------------------------------------
// K2: logits + 3x3 conv -> P = exp(conv - tile_row_max) stored in PV A-frag
// order, plus (mxt, sumP) per tile row. Kst/Ls LDS union (18.4 KB).
// ---------------------------------------------------------------------------
__global__ __launch_bounds__(320) void logits_conv_k(
    const bf16* __restrict__ qh, const bf16* __restrict__ kh,
    const float* __restrict__ kq_w, const float* __restrict__ kq_b,
    bf16* __restrict__ conv_out, float* __restrict__ tstats)
{
  const int tt = blockIdx.x;
  int qt = 0, base = 0;
  while (qt < 15 && base + qt + 2 <= tt) { base += qt + 2; ++qt; }
  const int ct = tt - base;
  const int h = blockIdx.y, b = blockIdx.z;
  const int q0 = qt * 64, c0 = ct * 64;
  __shared__ __align__(16) char un[18432];      // union: Kst then Ls
  bf16* Kst = (bf16*)un;                        // [80][72] bf16, staging
  float* Ls = (float*)un;                       // [66][68] f32, logits halo
  const int tid = threadIdx.x;
  const int lane = tid & 63, wid = tid >> 6;    // 5 waves
  const int q4 = lane >> 4, n16 = lane & 15;
  const bf16* qb = qh + ((size_t)(b * 16 + h) << 16);
  const bf16* kb = kh + ((size_t)(b * 16 + h) << 16);

  // ---- A-fragments straight from global (issue first, overlap staging) ----
  const int ar = min(max(q0 - 2 + wid * 16 + n16, 0), 1023);
  bf16x8 a0 = *(const bf16x8*)(qb + ar * 64 + q4 * 8);
  bf16x8 a1 = *(const bf16x8*)(qb + ar * 64 + 32 + q4 * 8);

  // ---- coalesced K staging (contiguous 10 KB span) ----
  for (int t = tid; t < 640; t += 320) {
    int row = t >> 3, ch = t & 7;
    int br = min(max(c0 - 1 + row, 0), 1023);
    *(uint4*)(&Kst[row * 72 + ch * 8]) = *(const uint4*)(kb + br * 64 + ch * 8);
  }
  __syncthreads();

  // ---- QK^T (B-frags from LDS) ----
  f32x4 acc[5] = {};
  #pragma unroll
  for (int c5 = 0; c5 < 5; ++c5) {
    int brow = c5 * 16 + n16;
    bf16x8 b0 = *(const bf16x8*)(&Kst[brow * 72 + q4 * 8]);
    bf16x8 b1 = *(const bf16x8*)(&Kst[brow * 72 + 32 + q4 * 8]);
    acc[c5] = __builtin_amdgcn_mfma_f32_16x16x32_bf16(a0, b0, acc[c5], 0, 0, 0);
    acc[c5] = __builtin_amdgcn_mfma_f32_16x16x32_bf16(a1, b1, acc[c5], 0, 0, 0);
  }
  __syncthreads();   // Kst reads complete before Ls overwrites the union

  #pragma unroll
  for (int c5 = 0; c5 < 5; ++c5) {
    #pragma unroll
    for (int r = 0; r < 4; ++r) {
      int Lrow = wid * 16 + q4 * 4 + r;
      int Lcol = c5 * 16 + n16;
      if (Lrow < 66 && Lcol < 66) {
        int rg = q0 - 2 + Lrow;
        int cg = c0 - 1 + Lcol;
        float v = (cg >= 0 && cg <= rg) ? acc[c5][r] * 0.125f : 0.f;
        Ls[Lrow * 68 + Lcol] = v;
      }
    }
  }
  __syncthreads();

  if (tid < 256) {
    float w9[9];
    #pragma unroll
    for (int i = 0; i < 9; ++i) w9[i] = kq_w[h * 9 + i];
    const float bb = kq_b[h];
    const size_t tplane = (size_t)(b * 16 + h) * 151 + base + ct;
    bf16* tb = conv_out + tplane * 4096;
    float2* st = (float2*)tstats + tplane * 64;

    const int r = tid >> 2, qr = tid & 3;   // output row, 16-col quarter
    float4 R0[5], R1[5], R2[5];
    const float* L0 = &Ls[r * 68 + qr * 16];
    #pragma unroll
    for (int i = 0; i < 5; ++i) {
      R0[i] = *(const float4*)(L0 + i * 4);
      R1[i] = *(const float4*)(L0 + 68 + i * 4);
      R2[i] = *(const float4*)(L0 + 136 + i * 4);
    }
    const float* f0 = (const float*)R0;
    const float* f1 = (const float*)R1;
    const float* f2 = (const float*)R2;
    float o[16];
    #pragma unroll
    for (int jj = 0; jj < 16; ++jj)
      o[jj] = bb + w9[0]*f0[jj] + w9[1]*f0[jj+1] + w9[2]*f0[jj+2]
                 + w9[3]*f1[jj] + w9[4]*f1[jj+1] + w9[5]*f1[jj+2]
                 + w9[6]*f2[jj] + w9[7]*f2[jj+1] + w9[8]*f2[jj+2];
    float mx = o[0];
    #pragma unroll
    for (int jj = 1; jj < 16; ++jj) mx = fmaxf(mx, o[jj]);
    mx = fmaxf(mx, __shfl_xor(mx, 1));
    mx = fmaxf(mx, __shfl_xor(mx, 2));
    unsigned int p[8];
    #pragma unroll
    for (int jj = 0; jj < 8; ++jj)
      p[jj] = cvt_pk_bf16(__expf(o[2*jj] - mx), __expf(o[2*jj+1] - mx));
    // store in PV A-frag order: [sr][kk][q4*16+n16][8]
    const int kk = qr >> 1, q4b = (qr & 1) * 2, sr = r >> 4, n16r = r & 15;
    *(uint4*)(tb + (sr * 2 + kk) * 512 + (q4b * 16 + n16r) * 8)       = *(const uint4*)&p[0];
    *(uint4*)(tb + (sr * 2 + kk) * 512 + ((q4b + 1) * 16 + n16r) * 8) = *(const uint4*)&p[4];
    float s = 0.f;
    #pragma unroll
    for (int jj = 0; jj < 8; ++jj) s += bf_lo(p[jj]) + bf_hi(p[jj]);
    s += __shfl_xor(s, 1);
    s += __shfl_xor(s, 2);
    if (qr == 0) st[r] = make_float2(mx, s);
  }
}

// ---------------------------------------------------------------------------
// K3a: combine per-tile stats -> per-row (max m, 1/l) incl. constant tail
// ---------------------------------------------------------------------------
__global__ __launch_bounds__(256) void combine_k(
    const float* __restrict__ tstats, const float* __restrict__ kq_b,
    float* __restrict__ rs)
{
  const int ridx = blockIdx.x * 256 + threadIdx.x;
  const int q = ridx & 1023, h = (ridx >> 10) & 15, plane = ridx >> 10;
  const int qt = q >> 6;
  const int nkt = min(qt + 2, 16);
  const int Tc = 1024 - (nkt << 6);
  const float2* ts = (const float2*)tstats +
      ((size_t)plane * 151 + (size_t)(qt * (qt + 3) / 2)) * 64 + (q & 63);
  const float kb = kq_b[h];
  float mx = (Tc > 0) ? kb : -3.0e38f;
  for (int kt = 0; kt < nkt; ++kt) mx = fmaxf(mx, ts[(size_t)kt * 64].x);
  float s = (float)Tc * __expf(kb - mx);
  for (int kt = 0; kt < nkt; ++kt) {
    float2 v = ts[(size_t)kt * 64];
    s += v.y * __expf(v.x - mx);
  }
  rs[(size_t)ridx * 2]     = mx;
  rs[(size_t)ridx * 2 + 1] = 1.f / s;
}

// ---------------------------------------------------------------------------
// K3b: PV from fragment-ordered P and V2 — every load 64-lane contiguous.
// A_o = sum_j (mw[o,j]*rinv_j*exp(mxt_j-m_j))*P_j
// ---------------------------------------------------------------------------
__global__ __launch_bounds__(256) void pv_k(
    const bf16* __restrict__ conv_out, const bf16* __restrict__ V2,
    const float* __restrict__ rs, const float* __restrict__ tstats,
    const float* __restrict__ Vtail,
    const float* __restrict__ mix_w, const float* __restrict__ mix_b,
    const float* __restrict__ kq_b,
    const float* __restrict__ dyt_alpha, const float* __restrict__ dyt_w,
    const float* __restrict__ dyt_b, const float* __restrict__ depth_scale,
    bf16* __restrict__ out_attn)
{
  const int qt16 = blockIdx.x, g = blockIdx.y, b = blockIdx.z;
  const int qt = qt16 >> 2;
  const int nkt = min(qt + 2, 16);
  const int Tc = 1024 - (nkt << 6);
  const int tid = threadIdx.x, lane = tid & 63, wid = tid >> 6;
  const int q4 = lane >> 4, n16 = lane & 15;
  const int oo = wid >> 1, kh = wid & 1;
  const int h0 = 2 * g, ho = h0 + oo;
  const int sr = qt16 & 3, strow = sr * 16;
  const size_t tbase = (size_t)(qt * (qt + 3) / 2);

  const int qrow = qt16 * 16 + n16;
  const float2 r0 = *(const float2*)(rs + ((((size_t)(b * 16 + h0)     << 10) + qrow) << 1));
  const float2 r1 = *(const float2*)(rs + ((((size_t)(b * 16 + h0 + 1) << 10) + qrow) << 1));
  const float m0 = r0.x, m1 = r1.x;
  const float mwa = mix_w[ho * 2 + 0], mwb = mix_w[ho * 2 + 1];
  const float wa = mwa * r0.y, wb = mwb * r1.y;   // mw * rinv

  const bf16* pb0 = conv_out +
      ((size_t)(b * 16 + h0) * 151 + tbase) * 4096 + sr * 1024 + lane * 8;
  const bf16* pb1 = pb0 + (size_t)151 * 4096;
  const float2* ts0 = (const float2*)tstats +
      ((size_t)(b * 16 + h0) * 151 + tbase) * 64 + strow + n16;
  const float2* ts1 = ts0 + (size_t)151 * 64;
  const bf16* vb = V2 + ((size_t)(b * 16 + ho) << 16) + lane * 8;

  const int niter = (nkt - kh + 1) >> 1;
  float wk0[8], wk1[8];
  #pragma unroll
  for (int i = 0; i < 8; ++i) {
    int ktc = (i < niter) ? (kh + 2 * i) : 0;
    wk0[i] = wa * __expf(ts0[(size_t)ktc * 64].x - m0);
    wk1[i] = wb * __expf(ts1[(size_t)ktc * 64].x - m1);
  }

  f32x4 acc[4] = {};
  int ii = 0;
  for (int kt = kh; kt < nkt; kt += 2, ++ii) {
    uint4 u0[2], u1[2];
    #pragma unroll
    for (int kk = 0; kk < 2; ++kk) {
      u0[kk] = *(const uint4*)(pb0 + (size_t)kt * 4096 + kk * 512);
      u1[kk] = *(const uint4*)(pb1 + (size_t)kt * 4096 + kk * 512);
    }
    bf16x8 bv[2][4];
    #pragma unroll
    for (int kk = 0; kk < 2; ++kk)
      #pragma unroll
      for (int ctt = 0; ctt < 4; ++ctt)
        bv[kk][ctt] = *(const bf16x8*)(vb + (size_t)kt * 4096 + kk * 2048 + ctt * 512);
    const float w0 = wk0[ii], w1 = wk1[ii];
    #pragma unroll
    for (int kk = 0; kk < 2; ++kk) {
      bf16x8 af;
      const unsigned int* a0p = (const unsigned int*)&u0[kk];
      const unsigned int* a1p = (const unsigned int*)&u1[kk];
      #pragma unroll
      for (int i2 = 0; i2 < 4; ++i2) {
        float a0 = w0 * bf_lo(a0p[i2]) + w1 * bf_lo(a1p[i2]);
        float a1 = w0 * bf_hi(a0p[i2]) + w1 * bf_hi(a1p[i2]);
        ((unsigned int*)&af)[i2] = cvt_pk_bf16(a0, a1);
      }
      #pragma unroll
      for (int ctt = 0; ctt < 4; ++ctt)
        acc[ctt] = __builtin_amdgcn_mfma_f32_16x16x32_bf16(af, bv[kk][ctt], acc[ctt], 0, 0, 0);
    }
  }

  __shared__ float Pp[2][16][64];
  if (kh == 1) {
    #pragma unroll
    for (int ctt = 0; ctt < 4; ++ctt)
      #pragma unroll
      for (int r = 0; r < 4; ++r)
        Pp[oo][q4 * 4 + r][ctt * 16 + n16] = acc[ctt][r];
  }
  __syncthreads();
  if (kh == 1) return;
  #pragma unroll
  for (int ctt = 0; ctt < 4; ++ctt)
    #pragma unroll
    for (int r = 0; r < 4; ++r)
      acc[ctt][r] += Pp[oo][q4 * 4 + r][ctt * 16 + n16];

  const float kqb0 = kq_b[h0], kqb1 = kq_b[h0 + 1];
  float tw[4];
  #pragma unroll
  for (int r = 0; r < 4; ++r) {
    int qr = qt16 * 16 + q4 * 4 + r;
    float2 s0 = *(const float2*)(rs + ((((size_t)(b * 16 + h0)     << 10) + qr) << 1));
    float2 s1 = *(const float2*)(rs + ((((size_t)(b * 16 + h0 + 1) << 10) + qr) << 1));
    tw[r] = (Tc > 0) ? (mwa * s0.y * __expf(kqb0 - s0.x) +
                        mwb * s1.y * __expf(kqb1 - s1.x)) : 0.f;
  }
  const float mb = mix_b[ho];
  const float alpha = dyt_alpha[0], dsc = depth_scale[0];
  const float* vt = Vtail + (size_t)(b * 16 + ho) * 17 * 64;
  #pragma unroll
  for (int ctt = 0; ctt < 4; ++ctt) {
    int d = ctt * 16 + n16;
    float vtn = vt[(size_t)nkt * 64 + d];
    float vt0 = vt[d];
    float wgt = dyt_w[d], bds = dyt_b[d];
    #pragma unroll
    for (int r = 0; r < 4; ++r) {
      float v = acc[ctt][r] + tw[r] * vtn + mb * vt0;
      float e = __expf(2.f * alpha * v);
      float th = 1.f - 2.f / (e + 1.f);
      float y = (th * wgt + bds) * dsc;
      int qr = qt16 * 16 + q4 * 4 + r;
      out_attn[(((size_t)(b * 1024 + qr)) << 10) + ho * 64 + d] = (bf16)y;
    }
  }
}

// ---------------------------------------------------------------------------
extern "C" void kernel_launch(void* const* d_in, const int* in_sizes, int n_in,
                              void* d_out, int out_size, void* d_ws, size_t ws_size,
                              hipStream_t stream) {
  const float* Q    = (const float*)d_in[0];
  const float* Kx   = (const float*)d_in[1];
  const float* V    = (const float*)d_in[2];
  const float* Wq   = (const float*)d_in[3];
  const float* bq   = (const float*)d_in[4];
  const float* Wk   = (const float*)d_in[5];
  const float* bk   = (const float*)d_in[6];
  const float* Wv   = (const float*)d_in[7];
  const float* bv   = (const float*)d_in[8];
  const float* Wo   = (const float*)d_in[9];
  const float* bo   = (const float*)d_in[10];
  const float* kq_w = (const float*)d_in[11];
  const float* kq_b = (const float*)d_in[12];
  const float* mixw = (const float*)d_in[13];
  const float* mixb = (const float*)d_in[14];
  const float* dyta = (const float*)d_in[15];
  const float* dytw = (const float*)d_in[16];
  const float* dytb = (const float*)d_in[17];
  const float* dsc  = (const float*)d_in[18];

  char* ws = (char*)d_ws;
  bf16* qh     = (bf16*)(ws);                              // 4 MB (kh, V2 follow)
  float* tstat = (float*)(ws + (size_t)(12 << 20));        // 2.42 MB (alive thru pv)
  float* Vtail = (float*)(ws + (size_t)(16 << 20));        // 136 KB
  float* Tsum  = (float*)(ws + (size_t)(16 << 20) + (256 << 10)); // 128 KB
  float* rsbuf = (float*)(ws + (size_t)(16 << 20) + (512 << 10)); // 256 KB
  bf16* WtT    = (bf16*)(ws + (size_t)(17 << 20));         // 8 MB (4 planes x 2MB)
  bf16* oat    = (bf16*)(ws + (size_t)(17 << 20));         // 4 MB, aliases Wq/Wk planes
  bf16* conv   = (bf16*)(ws + (size_t)(25 << 20));         // 39.58 MB (P2 tiles)
  bf16* Ab     = (bf16*)(ws + (size_t)(25 << 20));         // 12 MB, aliases conv (dead then)
  bf16* kh     = qh + ((size_t)1 << 21);
  bf16* V2     = qh + ((size_t)2 << 21);

  wtr_k<<<dim3(16, 16, 4), 256, 0, stream>>>(Wq, Wk, Wv, Wo, WtT);
  a2bf_k<<<dim3(1024, 3), 256, 0, stream>>>(Q, Kx, V, Ab);
  proj_gemm_k<<<dim3(256, 1, 3), 256, 0, stream>>>(Ab, WtT, bq, bk, bv, qh);
  vtile_sum_k<<<dim3(16, 16, 2), 64, 0, stream>>>(V2, Tsum);
  vtail_k<<<dim3(16, 2), 64, 0, stream>>>(Tsum, Vtail);
  logits_conv_k<<<dim3(151, 16, 2), 320, 0, stream>>>(qh, kh, kq_w, kq_b, conv, tstat);
  combine_k<<<dim3(128), 256, 0, stream>>>(tstat, kq_b, rsbuf);
  pv_k<<<dim3(64, 8, 2), 256, 0, stream>>>(conv, V2, rsbuf, tstat, Vtail, mixw, mixb, kq_b,
                                           dyta, dytw, dytb, dsc, oat);
  out_gemm_k<<<dim3(512), 256, 0, stream>>>(oat, WtT + ((size_t)3 << 20), bo, (float*)d_out);
}

// Round 2
// 212.590 us; speedup vs baseline: 1.0387x; 1.0283x over previous
//
#include <hip/hip_runtime.h>
#include <cstdint>
#include <cstddef>

typedef __bf16 bf16;
typedef __bf16 bf16x8 __attribute__((ext_vector_type(8)));
typedef float f32x4 __attribute__((ext_vector_type(4)));

#define DEVI static __device__ __forceinline__

// pack two f32 -> two bf16 (RTNE) in one uint
DEVI unsigned int cvt_pk_bf16(float lo, float hi) {
  unsigned int bl = __float_as_uint(lo);
  bl += 0x7fffu + ((bl >> 16) & 1u);
  unsigned int bh = __float_as_uint(hi);
  bh += 0x7fffu + ((bh >> 16) & 1u);
  return (bl >> 16) | (bh & 0xffff0000u);
}
DEVI float bf_lo(unsigned int u) { return __uint_as_float(u << 16); }
DEVI float bf_hi(unsigned int u) { return __uint_as_float(u & 0xffff0000u); }

// async global->LDS, 16B per lane; LDS dest = wave-uniform base + lane*16
DEVI void gload16(const bf16* g, bf16* l) {
  __builtin_amdgcn_global_load_lds(
      (const __attribute__((address_space(1))) unsigned int*)g,
      (__attribute__((address_space(3))) unsigned int*)l, 16, 0, 0);
}

// ---------------------------------------------------------------------------
// Fused prepass: bid<1024 -> W transpose (f32 [k][n] -> bf16 [n][k]);
// bid>=1024 -> Q/K/V f32 -> bf16 row-major. One launch, overlapped.
// ---------------------------------------------------------------------------
__global__ __launch_bounds__(256) void prep_k(
    const float* __restrict__ Wq, const float* __restrict__ Wk,
    const float* __restrict__ Wv, const float* __restrict__ Wo,
    const float* __restrict__ Q, const float* __restrict__ K,
    const float* __restrict__ V, bf16* __restrict__ Wt,
    bf16* __restrict__ Ab)
{
  __shared__ bf16 Ts[64 * 72];
  const int bid = blockIdx.x, tid = threadIdx.x;
  if (bid < 1024) {
    const int z = bid >> 8;
    const float* W = (z == 0) ? Wq : (z == 1) ? Wk : (z == 2) ? Wv : Wo;
    bf16* out = Wt + ((size_t)z << 20);
    const int n0 = (bid & 15) * 64, k0 = ((bid >> 4) & 15) * 64;
    #pragma unroll
    for (int i = 0; i < 4; ++i) {
      int t = tid + i * 256;
      int kr = t >> 4, nc = t & 15;
      float4 v = *(const float4*)(W + (size_t)(k0 + kr) * 1024 + n0 + nc * 4);
      Ts[(nc * 4 + 0) * 72 + kr] = (bf16)v.x;
      Ts[(nc * 4 + 1) * 72 + kr] = (bf16)v.y;
      Ts[(nc * 4 + 2) * 72 + kr] = (bf16)v.z;
      Ts[(nc * 4 + 3) * 72 + kr] = (bf16)v.w;
    }
    __syncthreads();
    const int n = tid >> 2, kc = tid & 3;
    *(uint4*)(out + (size_t)(n0 + n) * 1024 + k0 + kc * 16) =
        *(const uint4*)(&Ts[n * 72 + kc * 16]);
    *(uint4*)(out + (size_t)(n0 + n) * 1024 + k0 + kc * 16 + 8) =
        *(const uint4*)(&Ts[n * 72 + kc * 16 + 8]);
  } else {
    const int t = bid - 1024;              // 0..3071
    const int z = t >> 10, x = t & 1023;
    const float* A = (z == 0) ? Q : (z == 1) ? K : V;
    bf16* o = Ab + ((size_t)z << 21);
    const size_t idx = (size_t)x * 256 + tid;
    const float4 v0 = *(const float4*)(A + idx * 8);
    const float4 v1 = *(const float4*)(A + idx * 8 + 4);
    uint4 u;
    u.x = cvt_pk_bf16(v0.x, v0.y);
    u.y = cvt_pk_bf16(v0.z, v0.w);
    u.z = cvt_pk_bf16(v1.x, v1.y);
    u.w = cvt_pk_bf16(v1.z, v1.w);
    *(uint4*)(o + idx * 8) = u;
  }
}

// ---------------------------------------------------------------------------
// Fused projection GEMM, bf16 A, 128x64 tile, BK=64 (16 K-steps: half the
// barrier-drain latency exposures vs BK=32). global_load_lds both operands;
// source pre-swizzle kc^(row&7) so linear LDS reads are 2-way (free).
// grid (256,1,3): m-tile fastest -> A-stripe sharers land on one XCD.
// ---------------------------------------------------------------------------
__global__ __launch_bounds__(256) void proj_gemm_k(
    const bf16* __restrict__ Ab, const bf16* __restrict__ Wt,
    const float* __restrict__ bq, const float* __restrict__ bk,
    const float* __restrict__ bv, bf16* __restrict__ outbase)
{
  const int z = blockIdx.z;
  const bf16* A  = Ab + ((size_t)z << 21);
  const bf16* Bt = Wt + ((size_t)z << 20);
  const float* bias = (z == 0) ? bq : (z == 1) ? bk : bv;
  bf16* outb = outbase + ((size_t)z << 21);

  __shared__ __align__(16) bf16 Asm[2][8192];   // [128][64] per buffer
  __shared__ __align__(16) bf16 Bsm[2][4096];   // [64][64]  per buffer

  const int tid = threadIdx.x, lane = tid & 63, wid = tid >> 6;
  const int q4 = lane >> 4, n16 = lane & 15;
  const int wm = wid >> 1, wn = wid & 1;
  const int bid = blockIdx.x;
  const int m0 = (bid & 15) * 128, n0 = (bid >> 4) * 64;   // m fastest: XCD reuse

  // staging: chunk cc -> LDS elem cc*8 ; global row cc>>3, k-chunk (cc&7)^(row&7)
  const int cbase = wid * 64 + lane;
  const bf16* gA[4];
  #pragma unroll
  for (int i = 0; i < 4; ++i) {
    int cc = cbase + i * 256;
    gA[i] = A + (size_t)(m0 + (cc >> 3)) * 1024 + (((cc & 7) ^ ((cc >> 3) & 7)) << 3);
  }
  const bf16* gB[2];
  #pragma unroll
  for (int i = 0; i < 2; ++i) {
    int cc = cbase + i * 256;
    gB[i] = Bt + (size_t)(n0 + (cc >> 3)) * 1024 + (((cc & 7) ^ ((cc >> 3) & 7)) << 3);
  }
  const int swl = n16 & 7;   // read-side row swizzle key

  f32x4 acc[4][2] = {};

  // prologue: stage tile 0 -> buf 0
  #pragma unroll
  for (int i = 0; i < 4; ++i) gload16(gA[i], &Asm[0][i * 2048 + wid * 512]);
  #pragma unroll
  for (int i = 0; i < 2; ++i) gload16(gB[i], &Bsm[0][i * 2048 + wid * 512]);
  __syncthreads();

  int cur = 0;
  for (int t = 0; t < 16; ++t) {
    if (t < 15) {
      const int kc = (t + 1) * 64;
      #pragma unroll
      for (int i = 0; i < 4; ++i) gload16(gA[i] + kc, &Asm[cur ^ 1][i * 2048 + wid * 512]);
      #pragma unroll
      for (int i = 0; i < 2; ++i) gload16(gB[i] + kc, &Bsm[cur ^ 1][i * 2048 + wid * 512]);
    }
    const char* ab = (const char*)&Asm[cur][0];
    const char* bb = (const char*)&Bsm[cur][0];
    bf16x8 af[2][4], bfv[2][2];
    #pragma unroll
    for (int kk2 = 0; kk2 < 2; ++kk2) {
      #pragma unroll
      for (int rt = 0; rt < 4; ++rt)
        af[kk2][rt] = *(const bf16x8*)(ab + (wm * 64 + rt * 16 + n16) * 128 +
                                       (((kk2 * 4 + q4) ^ swl) << 4));
      #pragma unroll
      for (int ct = 0; ct < 2; ++ct)
        bfv[kk2][ct] = *(const bf16x8*)(bb + (wn * 32 + ct * 16 + n16) * 128 +
                                        (((kk2 * 4 + q4) ^ swl) << 4));
    }
    #pragma unroll
    for (int kk2 = 0; kk2 < 2; ++kk2)
      #pragma unroll
      for (int rt = 0; rt < 4; ++rt)
        #pragma unroll
        for (int ct = 0; ct < 2; ++ct)
          acc[rt][ct] = __builtin_amdgcn_mfma_f32_16x16x32_bf16(af[kk2][rt], bfv[kk2][ct], acc[rt][ct], 0, 0, 0);
    __syncthreads();
    cur ^= 1;
  }

  if (z < 2) {   // (B,H,S,HD)
    const int h = n0 >> 6;
    #pragma unroll
    for (int ct = 0; ct < 2; ++ct) {
      const int dl = wn * 32 + ct * 16 + n16;
      const float bvl = bias[n0 + dl];
      #pragma unroll
      for (int rt = 0; rt < 4; ++rt) {
        #pragma unroll
        for (int r = 0; r < 4; ++r) {
          int row = m0 + wm * 64 + rt * 16 + q4 * 4 + r;
          int b2 = row >> 10, s = row & 1023;
          outb[((size_t)((b2 * 16 + h) * 1024 + s) << 6) + dl] =
              (bf16)(acc[rt][ct][r] + bvl);
        }
      }
    }
  } else {       // V2 fragment layout, direct coalesced 8B stores
    const int b2 = m0 >> 10, kt0 = (m0 & 1023) >> 6, hh = n0 >> 6;
    bf16* vout = outb + ((size_t)(b2 * 16 + hh) << 16) + (size_t)(kt0 + wm) * 4096;
    #pragma unroll
    for (int rt = 0; rt < 4; ++rt) {
      const int kk = rt >> 1;
      const int q4c = (rt & 1) * 2 + (q4 >> 1);
      const int jo = (q4 & 1) * 4;
      #pragma unroll
      for (int ct = 0; ct < 2; ++ct) {
        const int cl = wn * 32 + ct * 16 + n16;
        const float bvl = bias[n0 + cl];
        unsigned int p0 = cvt_pk_bf16(acc[rt][ct][0] + bvl, acc[rt][ct][1] + bvl);
        unsigned int p1 = cvt_pk_bf16(acc[rt][ct][2] + bvl, acc[rt][ct][3] + bvl);
        *(uint2*)(vout + kk * 2048 + (wn * 2 + ct) * 512 + (q4c * 16 + n16) * 8 + jo) =
            make_uint2(p0, p1);
      }
    }
  }
}

// ---------------------------------------------------------------------------
// Output GEMM: d_out = oat(2048x1024 bf16) @ WoT + bo, f32 out.
// 64x64 tile, BK=64, same gload_lds + source-swizzle structure. 512 blocks.
// ---------------------------------------------------------------------------
__global__ __launch_bounds__(256) void out_gemm_k(
    const bf16* __restrict__ Ab, const bf16* __restrict__ Bt,
    const float* __restrict__ bias, float* __restrict__ outf)
{
  __shared__ __align__(16) bf16 Asm[2][4096];
  __shared__ __align__(16) bf16 Bsm[2][4096];
  const int tid = threadIdx.x, lane = tid & 63, wid = tid >> 6;
  const int q4 = lane >> 4, n16 = lane & 15;
  const int wm = wid >> 1, wn = wid & 1;
  const int bid = blockIdx.x;
  const int m0 = (bid & 31) * 64, n0 = (bid >> 5) * 64;   // XCD swizzle
  const int cbase = wid * 64 + lane;
  const bf16* gA[2];
  const bf16* gB[2];
  #pragma unroll
  for (int i = 0; i < 2; ++i) {
    int cc = cbase + i * 256;
    gA[i] = Ab + (size_t)(m0 + (cc >> 3)) * 1024 + (((cc & 7) ^ ((cc >> 3) & 7)) << 3);
    gB[i] = Bt + (size_t)(n0 + (cc >> 3)) * 1024 + (((cc & 7) ^ ((cc >> 3) & 7)) << 3);
  }
  const int swl = n16 & 7;
  f32x4 acc[2][2] = {};

  #pragma unroll
  for (int i = 0; i < 2; ++i) {
    gload16(gA[i], &Asm[0][i * 2048 + wid * 512]);
    gload16(gB[i], &Bsm[0][i * 2048 + wid * 512]);
  }
  __syncthreads();

  int cur = 0;
  for (int t = 0; t < 16; ++t) {
    if (t < 15) {
      const int kc = (t + 1) * 64;
      #pragma unroll
      for (int i = 0; i < 2; ++i) {
        gload16(gA[i] + kc, &Asm[cur ^ 1][i * 2048 + wid * 512]);
        gload16(gB[i] + kc, &Bsm[cur ^ 1][i * 2048 + wid * 512]);
      }
    }
    const char* ab = (const char*)&Asm[cur][0];
    const char* bb = (const char*)&Bsm[cur][0];
    bf16x8 af[2][2], bfv[2][2];
    #pragma unroll
    for (int kk2 = 0; kk2 < 2; ++kk2) {
      #pragma unroll
      for (int rt = 0; rt < 2; ++rt)
        af[kk2][rt] = *(const bf16x8*)(ab + (wm * 32 + rt * 16 + n16) * 128 +
                                       (((kk2 * 4 + q4) ^ swl) << 4));
      #pragma unroll
      for (int ct = 0; ct < 2; ++ct)
        bfv[kk2][ct] = *(const bf16x8*)(bb + (wn * 32 + ct * 16 + n16) * 128 +
                                        (((kk2 * 4 + q4) ^ swl) << 4));
    }
    #pragma unroll
    for (int kk2 = 0; kk2 < 2; ++kk2)
      #pragma unroll
      for (int rt = 0; rt < 2; ++rt)
        #pragma unroll
        for (int ct = 0; ct < 2; ++ct)
          acc[rt][ct] = __builtin_amdgcn_mfma_f32_16x16x32_bf16(af[kk2][rt], bfv[kk2][ct], acc[rt][ct], 0, 0, 0);
    __syncthreads();
    cur ^= 1;
  }
  #pragma unroll
  for (int ct = 0; ct < 2; ++ct) {
    int col = n0 + wn * 32 + ct * 16 + n16;
    float bvl = bias[col];
    #pragma unroll
    for (int rt = 0; rt < 2; ++rt)
      #pragma unroll
      for (int r = 0; r < 4; ++r) {
        int row = m0 + wm * 32 + rt * 16 + q4 * 4 + r;
        outf[(size_t)row * 1024 + col] = acc[rt][ct][r] + bvl;
      }
  }
}

// ---------------------------------------------------------------------------
// Fused per-(b,h) V tile column sums + suffix scan (was vtile_sum + vtail).
// ---------------------------------------------------------------------------
__global__ void vsum_k(const bf16* __restrict__ V2, float* __restrict__ Vtail)
{
  const int h = blockIdx.x, b = blockIdx.y, d = threadIdx.x;
  const int ctt = d >> 4, n16c = d & 15;
  const bf16* p = V2 + ((size_t)(b * 16 + h) << 16) + ctt * 512 + n16c * 8;
  float ts[16];
  for (int kt = 0; kt < 16; ++kt) {
    float s = 0.f;
    #pragma unroll
    for (int kk = 0; kk < 2; ++kk)
      #pragma unroll
      for (int q4i = 0; q4i < 4; ++q4i)
        #pragma unroll
        for (int j = 0; j < 8; ++j)
          s += (float)p[kt * 4096 + kk * 2048 + q4i * 128 + j];
    ts[kt] = s;
  }
  float* vt = Vtail + (size_t)(b * 16 + h) * 17 * 64;
  vt[16 * 64 + d] = 0.f;
  float c = 0.f;
  for (int kt = 15; kt >= 0; --kt) {
    c += ts[kt];
    vt[kt * 64 + d] = c;
  }
}

// ---------------------------------------------------------------------------
// K2: logits + 3x3 conv -> P = exp(conv - tile_row_max) stored in PV A-frag
// order, plus (mxt, sumP) per tile row. Kst/Ls LDS union.
// Ls stride 72 floats: halo-read phase 4-way -> 2-way (free) bank aliasing.
// ---------------------------------------------------------------------------
__global__ __launch_bounds__(320) void logits_conv_k(
    const bf16* __restrict__ qh, const bf16* __restrict__ kh,
    const float* __restrict__ kq_w, const float* __restrict__ kq_b,
    bf16* __restrict__ conv_out, float* __restrict__ tstats)
{
  const int tt = blockIdx.x;
  int qt = 0, base = 0;
  while (qt < 15 && base + qt + 2 <= tt) { base += qt + 2; ++qt; }
  const int ct = tt - base;
  const int h = blockIdx.y, b = blockIdx.z;
  const int q0 = qt * 64, c0 = ct * 64;
  __shared__ __align__(16) char un[19456];      // union: Kst then Ls
  bf16* Kst = (bf16*)un;                        // [80][72] bf16, staging
  float* Ls = (float*)un;                       // [66][72] f32, logits halo
  const int tid = threadIdx.x;
  const int lane = tid & 63, wid = tid >> 6;    // 5 waves
  const int q4 = lane >> 4, n16 = lane & 15;
  const bf16* qb = qh + ((size_t)(b * 16 + h) << 16);
  const bf16* kb = kh + ((size_t)(b * 16 + h) << 16);

  // ---- A-fragments straight from global (issue first, overlap staging) ----
  const int ar = min(max(q0 - 2 + wid * 16 + n16, 0), 1023);
  bf16x8 a0 = *(const bf16x8*)(qb + ar * 64 + q4 * 8);
  bf16x8 a1 = *(const bf16x8*)(qb + ar * 64 + 32 + q4 * 8);

  // ---- coalesced K staging (contiguous 10 KB span) ----
  for (int t = tid; t < 640; t += 320) {
    int row = t >> 3, ch = t & 7;
    int br = min(max(c0 - 1 + row, 0), 1023);
    *(uint4*)(&Kst[row * 72 + ch * 8]) = *(const uint4*)(kb + br * 64 + ch * 8);
  }
  __syncthreads();

  // ---- QK^T (B-frags from LDS) ----
  f32x4 acc[5] = {};
  #pragma unroll
  for (int c5 = 0; c5 < 5; ++c5) {
    int brow = c5 * 16 + n16;
    bf16x8 b0 = *(const bf16x8*)(&Kst[brow * 72 + q4 * 8]);
    bf16x8 b1 = *(const bf16x8*)(&Kst[brow * 72 + 32 + q4 * 8]);
    acc[c5] = __builtin_amdgcn_mfma_f32_16x16x32_bf16(a0, b0, acc[c5], 0, 0, 0);
    acc[c5] = __builtin_amdgcn_mfma_f32_16x16x32_bf16(a1, b1, acc[c5], 0, 0, 0);
  }
  __syncthreads();   // Kst reads complete before Ls overwrites the union

  #pragma unroll
  for (int c5 = 0; c5 < 5; ++c5) {
    #pragma unroll
    for (int r = 0; r < 4; ++r) {
      int Lrow = wid * 16 + q4 * 4 + r;
      int Lcol = c5 * 16 + n16;
      if (Lrow < 66 && Lcol < 66) {
        int rg = q0 - 2 + Lrow;
        int cg = c0 - 1 + Lcol;
        float v = (cg >= 0 && cg <= rg) ? acc[c5][r] * 0.125f : 0.f;
        Ls[Lrow * 72 + Lcol] = v;
      }
    }
  }
  __syncthreads();

  if (tid < 256) {
    float w9[9];
    #pragma unroll
    for (int i = 0; i < 9; ++i) w9[i] = kq_w[h * 9 + i];
    const float bb = kq_b[h];
    const size_t tplane = (size_t)(b * 16 + h) * 151 + base + ct;
    bf16* tb = conv_out + tplane * 4096;
    float2* st = (float2*)tstats + tplane * 64;

    const int r = tid >> 2, qr = tid & 3;   // output row, 16-col quarter
    float4 R0[5], R1[5], R2[5];
    const float* L0 = &Ls[r * 72 + qr * 16];
    #pragma unroll
    for (int i = 0; i < 5; ++i) {
      R0[i] = *(const float4*)(L0 + i * 4);
      R1[i] = *(const float4*)(L0 + 72 + i * 4);
      R2[i] = *(const float4*)(L0 + 144 + i * 4);
    }
    const float* f0 = (const float*)R0;
    const float* f1 = (const float*)R1;
    const float* f2 = (const float*)R2;
    float o[16];
    #pragma unroll
    for (int jj = 0; jj < 16; ++jj)
      o[jj] = bb + w9[0]*f0[jj] + w9[1]*f0[jj+1] + w9[2]*f0[jj+2]
                 + w9[3]*f1[jj] + w9[4]*f1[jj+1] + w9[5]*f1[jj+2]
                 + w9[6]*f2[jj] + w9[7]*f2[jj+1] + w9[8]*f2[jj+2];
    float mx = o[0];
    #pragma unroll
    for (int jj = 1; jj < 16; ++jj) mx = fmaxf(mx, o[jj]);
    mx = fmaxf(mx, __shfl_xor(mx, 1));
    mx = fmaxf(mx, __shfl_xor(mx, 2));
    unsigned int p[8];
    #pragma unroll
    for (int jj = 0; jj < 8; ++jj)
      p[jj] = cvt_pk_bf16(__expf(o[2*jj] - mx), __expf(o[2*jj+1] - mx));
    // store in PV A-frag order: [sr][kk][q4*16+n16][8]
    const int kk = qr >> 1, q4b = (qr & 1) * 2, sr = r >> 4, n16r = r & 15;
    *(uint4*)(tb + (sr * 2 + kk) * 512 + (q4b * 16 + n16r) * 8)       = *(const uint4*)&p[0];
    *(uint4*)(tb + (sr * 2 + kk) * 512 + ((q4b + 1) * 16 + n16r) * 8) = *(const uint4*)&p[4];
    float s = 0.f;
    #pragma unroll
    for (int jj = 0; jj < 8; ++jj) s += bf_lo(p[jj]) + bf_hi(p[jj]);
    s += __shfl_xor(s, 1);
    s += __shfl_xor(s, 2);
    if (qr == 0) st[r] = make_float2(mx, s);
  }
}

// ---------------------------------------------------------------------------
// K3b: PV from fragment-ordered P and V2, with per-row (m, 1/l) stats
// computed INLINE (was combine_k): each block owns exactly its 16 rows x
// 2 heads -> non-redundant fusion via LDS.
// ---------------------------------------------------------------------------
__global__ __launch_bounds__(256) void pv_k(
    const bf16* __restrict__ conv_out, const bf16* __restrict__ V2,
    const float* __restrict__ tstats, const float* __restrict__ Vtail,
    const float* __restrict__ mix_w, const float* __restrict__ mix_b,
    const float* __restrict__ kq_b,
    const float* __restrict__ dyt_alpha, const float* __restrict__ dyt_w,
    const float* __restrict__ dyt_b, const float* __restrict__ depth_scale,
    bf16* __restrict__ out_attn)
{
  const int qt16 = blockIdx.x, g = blockIdx.y, b = blockIdx.z;
  const int qt = qt16 >> 2;
  const int nkt = min(qt + 2, 16);
  const int Tc = 1024 - (nkt << 6);
  const int tid = threadIdx.x, lane = tid & 63, wid = tid >> 6;
  const int q4 = lane >> 4, n16 = lane & 15;
  const int oo = wid >> 1, kh = wid & 1;
  const int h0 = 2 * g, ho = h0 + oo;
  const int sr = qt16 & 3, strow = sr * 16;
  const size_t tbase = (size_t)(qt * (qt + 3) / 2);

  // ---- inline combine: per-row (m, 1/l) for this block's 16 rows x 2 heads
  __shared__ float2 rsS[2][16];
  if (tid < 32) {
    const int hh = tid >> 4, rw = tid & 15;
    const float2* tsp = (const float2*)tstats +
        ((size_t)(b * 16 + h0 + hh) * 151 + tbase) * 64 + strow + rw;
    const float kb2 = kq_b[h0 + hh];
    float mx = (Tc > 0) ? kb2 : -3.0e38f;
    for (int kt = 0; kt < nkt; ++kt) mx = fmaxf(mx, tsp[(size_t)kt * 64].x);
    float s = (float)Tc * __expf(kb2 - mx);
    for (int kt = 0; kt < nkt; ++kt) {
      float2 v = tsp[(size_t)kt * 64];
      s += v.y * __expf(v.x - mx);
    }
    rsS[hh][rw] = make_float2(mx, 1.f / s);
  }
  __syncthreads();

  const float2 r0 = rsS[0][n16];
  const float2 r1 = rsS[1][n16];
  const float m0 = r0.x, m1 = r1.x;
  const float mwa = mix_w[ho * 2 + 0], mwb = mix_w[ho * 2 + 1];
  const float wa = mwa * r0.y, wb = mwb * r1.y;   // mw * rinv

  const bf16* pb0 = conv_out +
      ((size_t)(b * 16 + h0) * 151 + tbase) * 4096 + sr * 1024 + lane * 8;
  const bf16* pb1 = pb0 + (size_t)151 * 4096;
  const float2* ts0 = (const float2*)tstats +
      ((size_t)(b * 16 + h0) * 151 + tbase) * 64 + strow + n16;
  const float2* ts1 = ts0 + (size_t)151 * 64;
  const bf16* vb = V2 + ((size_t)(b * 16 + ho) << 16) + lane * 8;

  const int niter = (nkt - kh + 1) >> 1;
  float wk0[8], wk1[8];
  #pragma unroll
  for (int i = 0; i < 8; ++i) {
    int ktc = (i < niter) ? (kh + 2 * i) : 0;
    wk0[i] = wa * __expf(ts0[(size_t)ktc * 64].x - m0);
    wk1[i] = wb * __expf(ts1[(size_t)ktc * 64].x - m1);
  }

  f32x4 acc[4] = {};
  int ii = 0;
  for (int kt = kh; kt < nkt; kt += 2, ++ii) {
    uint4 u0[2], u1[2];
    #pragma unroll
    for (int kk = 0; kk < 2; ++kk) {
      u0[kk] = *(const uint4*)(pb0 + (size_t)kt * 4096 + kk * 512);
      u1[kk] = *(const uint4*)(pb1 + (size_t)kt * 4096 + kk * 512);
    }
    bf16x8 bv[2][4];
    #pragma unroll
    for (int kk = 0; kk < 2; ++kk)
      #pragma unroll
      for (int ctt = 0; ctt < 4; ++ctt)
        bv[kk][ctt] = *(const bf16x8*)(vb + (size_t)kt * 4096 + kk * 2048 + ctt * 512);
    const float w0 = wk0[ii], w1 = wk1[ii];
    #pragma unroll
    for (int kk = 0; kk < 2; ++kk) {
      bf16x8 af;
      const unsigned int* a0p = (const unsigned int*)&u0[kk];
      const unsigned int* a1p = (const unsigned int*)&u1[kk];
      #pragma unroll
      for (int i2 = 0; i2 < 4; ++i2) {
        float a0 = w0 * bf_lo(a0p[i2]) + w1 * bf_lo(a1p[i2]);
        float a1 = w0 * bf_hi(a0p[i2]) + w1 * bf_hi(a1p[i2]);
        ((unsigned int*)&af)[i2] = cvt_pk_bf16(a0, a1);
      }
      #pragma unroll
      for (int ctt = 0; ctt < 4; ++ctt)
        acc[ctt] = __builtin_amdgcn_mfma_f32_16x16x32_bf16(af, bv[kk][ctt], acc[ctt], 0, 0, 0);
    }
  }

  __shared__ float Pp[2][16][64];
  if (kh == 1) {
    #pragma unroll
    for (int ctt = 0; ctt < 4; ++ctt)
      #pragma unroll
      for (int r = 0; r < 4; ++r)
        Pp[oo][q4 * 4 + r][ctt * 16 + n16] = acc[ctt][r];
  }
  __syncthreads();
  if (kh == 1) return;
  #pragma unroll
  for (int ctt = 0; ctt < 4; ++ctt)
    #pragma unroll
    for (int r = 0; r < 4; ++r)
      acc[ctt][r] += Pp[oo][q4 * 4 + r][ctt * 16 + n16];

  const float kqb0 = kq_b[h0], kqb1 = kq_b[h0 + 1];
  float tw[4];
  #pragma unroll
  for (int r = 0; r < 4; ++r) {
    float2 s0 = rsS[0][q4 * 4 + r];
    float2 s1 = rsS[1][q4 * 4 + r];
    tw[r] = (Tc > 0) ? (mwa * s0.y * __expf(kqb0 - s0.x) +
                        mwb * s1.y * __expf(kqb1 - s1.x)) : 0.f;
  }
  const float mb = mix_b[ho];
  const float alpha = dyt_alpha[0], dsc = depth_scale[0];
  const float* vt = Vtail + (size_t)(b * 16 + ho) * 17 * 64;
  #pragma unroll
  for (int ctt = 0; ctt < 4; ++ctt) {
    int d = ctt * 16 + n16;
    float vtn = vt[(size_t)nkt * 64 + d];
    float vt0 = vt[d];
    float wgt = dyt_w[d], bds = dyt_b[d];
    #pragma unroll
    for (int r = 0; r < 4; ++r) {
      float v = acc[ctt][r] + tw[r] * vtn + mb * vt0;
      float e = __expf(2.f * alpha * v);
      float th = 1.f - 2.f / (e + 1.f);
      float y = (th * wgt + bds) * dsc;
      int qr = qt16 * 16 + q4 * 4 + r;
      out_attn[(((size_t)(b * 1024 + qr)) << 10) + ho * 64 + d] = (bf16)y;
    }
  }
}

// ---------------------------------------------------------------------------
extern "C" void kernel_launch(void* const* d_in, const int* in_sizes, int n_in,
                              void* d_out, int out_size, void* d_ws, size_t ws_size,
                              hipStream_t stream) {
  const float* Q    = (const float*)d_in[0];
  const float* Kx   = (const float*)d_in[1];
  const float* V    = (const float*)d_in[2];
  const float* Wq   = (const float*)d_in[3];
  const float* bq   = (const float*)d_in[4];
  const float* Wk   = (const float*)d_in[5];
  const float* bk   = (const float*)d_in[6];
  const float* Wv   = (const float*)d_in[7];
  const float* bv   = (const float*)d_in[8];
  const float* Wo   = (const float*)d_in[9];
  const float* bo   = (const float*)d_in[10];
  const float* kq_w = (const float*)d_in[11];
  const float* kq_b = (const float*)d_in[12];
  const float* mixw = (const float*)d_in[13];
  const float* mixb = (const float*)d_in[14];
  const float* dyta = (const float*)d_in[15];
  const float* dytw = (const float*)d_in[16];
  const float* dytb = (const float*)d_in[17];
  const float* dsc  = (const float*)d_in[18];

  char* ws = (char*)d_ws;
  bf16* qh     = (bf16*)(ws);                              // 4 MB (kh, V2 follow)
  float* tstat = (float*)(ws + (size_t)(12 << 20));        // 2.42 MB (alive thru pv)
  float* Vtail = (float*)(ws + (size_t)(16 << 20));        // 136 KB
  bf16* WtT    = (bf16*)(ws + (size_t)(17 << 20));         // 8 MB (4 planes x 2MB)
  bf16* oat    = (bf16*)(ws + (size_t)(17 << 20));         // 4 MB, aliases Wq/Wk planes
  bf16* conv   = (bf16*)(ws + (size_t)(25 << 20));         // 39.58 MB (P2 tiles)
  bf16* Ab     = (bf16*)(ws + (size_t)(25 << 20));         // 12 MB, aliases conv (dead then)
  bf16* kh     = qh + ((size_t)1 << 21);
  bf16* V2     = qh + ((size_t)2 << 21);

  prep_k<<<dim3(4096), 256, 0, stream>>>(Wq, Wk, Wv, Wo, Q, Kx, V, WtT, Ab);
  proj_gemm_k<<<dim3(256, 1, 3), 256, 0, stream>>>(Ab, WtT, bq, bk, bv, qh);
  vsum_k<<<dim3(16, 2), 64, 0, stream>>>(V2, Vtail);
  logits_conv_k<<<dim3(151, 16, 2), 320, 0, stream>>>(qh, kh, kq_w, kq_b, conv, tstat);
  pv_k<<<dim3(64, 8, 2), 256, 0, stream>>>(conv, V2, tstat, Vtail, mixw, mixb, kq_b,
                                           dyta, dytw, dytb, dsc, oat);
  out_gemm_k<<<dim3(512), 256, 0, stream>>>(oat, WtT + ((size_t)3 << 20), bo, (float*)d_out);
}

// Round 3
// 204.487 us; speedup vs baseline: 1.0799x; 1.0396x over previous
//
#include <hip/hip_runtime.h>
#include <cstdint>
#include <cstddef>

typedef __bf16 bf16;
typedef __bf16 bf16x8 __attribute__((ext_vector_type(8)));
typedef float f32x4 __attribute__((ext_vector_type(4)));

#define DEVI static __device__ __forceinline__

// pack two f32 -> two bf16 (RTNE) in one uint
DEVI unsigned int cvt_pk_bf16(float lo, float hi) {
  unsigned int bl = __float_as_uint(lo);
  bl += 0x7fffu + ((bl >> 16) & 1u);
  unsigned int bh = __float_as_uint(hi);
  bh += 0x7fffu + ((bh >> 16) & 1u);
  return (bl >> 16) | (bh & 0xffff0000u);
}
DEVI float bf_lo(unsigned int u) { return __uint_as_float(u << 16); }
DEVI float bf_hi(unsigned int u) { return __uint_as_float(u & 0xffff0000u); }

// async global->LDS, 16B per lane; LDS dest = wave-uniform base + lane*16
DEVI void gload16(const bf16* g, bf16* l) {
  __builtin_amdgcn_global_load_lds(
      (const __attribute__((address_space(1))) unsigned int*)g,
      (__attribute__((address_space(3))) unsigned int*)l, 16, 0, 0);
}

// ---------------------------------------------------------------------------
// Fused prepass: bid<1024 -> W transpose (f32 [k][n] -> bf16 [n][k]);
// bid>=1024 -> Q/K/V f32 -> bf16 row-major. One launch, overlapped.
// ---------------------------------------------------------------------------
__global__ __launch_bounds__(256) void prep_k(
    const float* __restrict__ Wq, const float* __restrict__ Wk,
    const float* __restrict__ Wv, const float* __restrict__ Wo,
    const float* __restrict__ Q, const float* __restrict__ K,
    const float* __restrict__ V, bf16* __restrict__ Wt,
    bf16* __restrict__ Ab)
{
  __shared__ bf16 Ts[64 * 72];
  const int bid = blockIdx.x, tid = threadIdx.x;
  if (bid < 1024) {
    const int z = bid >> 8;
    const float* W = (z == 0) ? Wq : (z == 1) ? Wk : (z == 2) ? Wv : Wo;
    bf16* out = Wt + ((size_t)z << 20);
    const int n0 = (bid & 15) * 64, k0 = ((bid >> 4) & 15) * 64;
    #pragma unroll
    for (int i = 0; i < 4; ++i) {
      int t = tid + i * 256;
      int kr = t >> 4, nc = t & 15;
      float4 v = *(const float4*)(W + (size_t)(k0 + kr) * 1024 + n0 + nc * 4);
      Ts[(nc * 4 + 0) * 72 + kr] = (bf16)v.x;
      Ts[(nc * 4 + 1) * 72 + kr] = (bf16)v.y;
      Ts[(nc * 4 + 2) * 72 + kr] = (bf16)v.z;
      Ts[(nc * 4 + 3) * 72 + kr] = (bf16)v.w;
    }
    __syncthreads();
    const int n = tid >> 2, kc = tid & 3;
    *(uint4*)(out + (size_t)(n0 + n) * 1024 + k0 + kc * 16) =
        *(const uint4*)(&Ts[n * 72 + kc * 16]);
    *(uint4*)(out + (size_t)(n0 + n) * 1024 + k0 + kc * 16 + 8) =
        *(const uint4*)(&Ts[n * 72 + kc * 16 + 8]);
  } else {
    const int t = bid - 1024;              // 0..3071
    const int z = t >> 10, x = t & 1023;
    const float* A = (z == 0) ? Q : (z == 1) ? K : V;
    bf16* o = Ab + ((size_t)z << 21);
    const size_t idx = (size_t)x * 256 + tid;
    const float4 v0 = *(const float4*)(A + idx * 8);
    const float4 v1 = *(const float4*)(A + idx * 8 + 4);
    uint4 u;
    u.x = cvt_pk_bf16(v0.x, v0.y);
    u.y = cvt_pk_bf16(v0.z, v0.w);
    u.z = cvt_pk_bf16(v1.x, v1.y);
    u.w = cvt_pk_bf16(v1.z, v1.w);
    *(uint4*)(o + idx * 8) = u;
  }
}

// ---------------------------------------------------------------------------
// Fused projection GEMM, bf16 A, 128x64 tile, BK=64. global_load_lds both
// operands; source pre-swizzle kc^(row&7) so linear LDS reads are 2-way.
// grid (256,1,3): m-tile fastest -> A-stripe sharers land on one XCD.
// z=2 epilogue also emits per-(tile,col) V column sums to Tsum in-register
// (each Tsum entry has exactly ONE writer block -> plain stores, no vsum
// kernel, no 8MB V2 re-read).
// ---------------------------------------------------------------------------
__global__ __launch_bounds__(256) void proj_gemm_k(
    const bf16* __restrict__ Ab, const bf16* __restrict__ Wt,
    const float* __restrict__ bq, const float* __restrict__ bk,
    const float* __restrict__ bv, bf16* __restrict__ outbase,
    float* __restrict__ Tsum)
{
  const int z = blockIdx.z;
  const bf16* A  = Ab + ((size_t)z << 21);
  const bf16* Bt = Wt + ((size_t)z << 20);
  const float* bias = (z == 0) ? bq : (z == 1) ? bk : bv;
  bf16* outb = outbase + ((size_t)z << 21);

  __shared__ __align__(16) bf16 Asm[2][8192];   // [128][64] per buffer
  __shared__ __align__(16) bf16 Bsm[2][4096];   // [64][64]  per buffer

  const int tid = threadIdx.x, lane = tid & 63, wid = tid >> 6;
  const int q4 = lane >> 4, n16 = lane & 15;
  const int wm = wid >> 1, wn = wid & 1;
  const int bid = blockIdx.x;
  const int m0 = (bid & 15) * 128, n0 = (bid >> 4) * 64;   // m fastest: XCD reuse

  // staging: chunk cc -> LDS elem cc*8 ; global row cc>>3, k-chunk (cc&7)^(row&7)
  const int cbase = wid * 64 + lane;
  const bf16* gA[4];
  #pragma unroll
  for (int i = 0; i < 4; ++i) {
    int cc = cbase + i * 256;
    gA[i] = A + (size_t)(m0 + (cc >> 3)) * 1024 + (((cc & 7) ^ ((cc >> 3) & 7)) << 3);
  }
  const bf16* gB[2];
  #pragma unroll
  for (int i = 0; i < 2; ++i) {
    int cc = cbase + i * 256;
    gB[i] = Bt + (size_t)(n0 + (cc >> 3)) * 1024 + (((cc & 7) ^ ((cc >> 3) & 7)) << 3);
  }
  const int swl = n16 & 7;   // read-side row swizzle key

  f32x4 acc[4][2] = {};

  // prologue: stage tile 0 -> buf 0
  #pragma unroll
  for (int i = 0; i < 4; ++i) gload16(gA[i], &Asm[0][i * 2048 + wid * 512]);
  #pragma unroll
  for (int i = 0; i < 2; ++i) gload16(gB[i], &Bsm[0][i * 2048 + wid * 512]);
  __syncthreads();

  int cur = 0;
  for (int t = 0; t < 16; ++t) {
    if (t < 15) {
      const int kc = (t + 1) * 64;
      #pragma unroll
      for (int i = 0; i < 4; ++i) gload16(gA[i] + kc, &Asm[cur ^ 1][i * 2048 + wid * 512]);
      #pragma unroll
      for (int i = 0; i < 2; ++i) gload16(gB[i] + kc, &Bsm[cur ^ 1][i * 2048 + wid * 512]);
    }
    const char* ab = (const char*)&Asm[cur][0];
    const char* bb = (const char*)&Bsm[cur][0];
    bf16x8 af[2][4], bfv[2][2];
    #pragma unroll
    for (int kk2 = 0; kk2 < 2; ++kk2) {
      #pragma unroll
      for (int rt = 0; rt < 4; ++rt)
        af[kk2][rt] = *(const bf16x8*)(ab + (wm * 64 + rt * 16 + n16) * 128 +
                                       (((kk2 * 4 + q4) ^ swl) << 4));
      #pragma unroll
      for (int ct = 0; ct < 2; ++ct)
        bfv[kk2][ct] = *(const bf16x8*)(bb + (wn * 32 + ct * 16 + n16) * 128 +
                                        (((kk2 * 4 + q4) ^ swl) << 4));
    }
    #pragma unroll
    for (int kk2 = 0; kk2 < 2; ++kk2)
      #pragma unroll
      for (int rt = 0; rt < 4; ++rt)
        #pragma unroll
        for (int ct = 0; ct < 2; ++ct)
          acc[rt][ct] = __builtin_amdgcn_mfma_f32_16x16x32_bf16(af[kk2][rt], bfv[kk2][ct], acc[rt][ct], 0, 0, 0);
    __syncthreads();
    cur ^= 1;
  }

  if (z < 2) {   // (B,H,S,HD)
    const int h = n0 >> 6;
    #pragma unroll
    for (int ct = 0; ct < 2; ++ct) {
      const int dl = wn * 32 + ct * 16 + n16;
      const float bvl = bias[n0 + dl];
      #pragma unroll
      for (int rt = 0; rt < 4; ++rt) {
        #pragma unroll
        for (int r = 0; r < 4; ++r) {
          int row = m0 + wm * 64 + rt * 16 + q4 * 4 + r;
          int b2 = row >> 10, s = row & 1023;
          outb[((size_t)((b2 * 16 + h) * 1024 + s) << 6) + dl] =
              (bf16)(acc[rt][ct][r] + bvl);
        }
      }
    }
  } else {       // V2 fragment layout + in-register column sums -> Tsum
    const int b2 = m0 >> 10, kt0 = (m0 & 1023) >> 6, hh = n0 >> 6;
    bf16* vout = outb + ((size_t)(b2 * 16 + hh) << 16) + (size_t)(kt0 + wm) * 4096;
    float csum[2] = {0.f, 0.f};
    #pragma unroll
    for (int rt = 0; rt < 4; ++rt) {
      const int kk = rt >> 1;
      const int q4c = (rt & 1) * 2 + (q4 >> 1);
      const int jo = (q4 & 1) * 4;
      #pragma unroll
      for (int ct = 0; ct < 2; ++ct) {
        const int cl = wn * 32 + ct * 16 + n16;
        const float bvl = bias[n0 + cl];
        unsigned int p0 = cvt_pk_bf16(acc[rt][ct][0] + bvl, acc[rt][ct][1] + bvl);
        unsigned int p1 = cvt_pk_bf16(acc[rt][ct][2] + bvl, acc[rt][ct][3] + bvl);
        csum[ct] += bf_lo(p0) + bf_hi(p0) + bf_lo(p1) + bf_hi(p1);
        *(uint2*)(vout + kk * 2048 + (wn * 2 + ct) * 512 + (q4c * 16 + n16) * 8 + jo) =
            make_uint2(p0, p1);
      }
    }
    // reduce over the 64 rows this wave covers: in-lane (rt,r) done above;
    // cross-lane over q4 (lane bits 4,5)
    #pragma unroll
    for (int ct = 0; ct < 2; ++ct) {
      csum[ct] += __shfl_xor(csum[ct], 16);
      csum[ct] += __shfl_xor(csum[ct], 32);
    }
    if (lane < 16) {
      float* tsd = Tsum + ((size_t)(b2 * 16 + hh) * 16 + kt0 + wm) * 64 + wn * 32 + n16;
      tsd[0]  = csum[0];
      tsd[16] = csum[1];
    }
  }
}

// ---------------------------------------------------------------------------
// Output GEMM: d_out = oat(2048x1024 bf16) @ WoT + bo, f32 out.
// 64x64 tile, BK=64, same gload_lds + source-swizzle structure. 512 blocks.
// ---------------------------------------------------------------------------
__global__ __launch_bounds__(256) void out_gemm_k(
    const bf16* __restrict__ Ab, const bf16* __restrict__ Bt,
    const float* __restrict__ bias, float* __restrict__ outf)
{
  __shared__ __align__(16) bf16 Asm[2][4096];
  __shared__ __align__(16) bf16 Bsm[2][4096];
  const int tid = threadIdx.x, lane = tid & 63, wid = tid >> 6;
  const int q4 = lane >> 4, n16 = lane & 15;
  const int wm = wid >> 1, wn = wid & 1;
  const int bid = blockIdx.x;
  const int m0 = (bid & 31) * 64, n0 = (bid >> 5) * 64;   // XCD swizzle
  const int cbase = wid * 64 + lane;
  const bf16* gA[2];
  const bf16* gB[2];
  #pragma unroll
  for (int i = 0; i < 2; ++i) {
    int cc = cbase + i * 256;
    gA[i] = Ab + (size_t)(m0 + (cc >> 3)) * 1024 + (((cc & 7) ^ ((cc >> 3) & 7)) << 3);
    gB[i] = Bt + (size_t)(n0 + (cc >> 3)) * 1024 + (((cc & 7) ^ ((cc >> 3) & 7)) << 3);
  }
  const int swl = n16 & 7;
  f32x4 acc[2][2] = {};

  #pragma unroll
  for (int i = 0; i < 2; ++i) {
    gload16(gA[i], &Asm[0][i * 2048 + wid * 512]);
    gload16(gB[i], &Bsm[0][i * 2048 + wid * 512]);
  }
  __syncthreads();

  int cur = 0;
  for (int t = 0; t < 16; ++t) {
    if (t < 15) {
      const int kc = (t + 1) * 64;
      #pragma unroll
      for (int i = 0; i < 2; ++i) {
        gload16(gA[i] + kc, &Asm[cur ^ 1][i * 2048 + wid * 512]);
        gload16(gB[i] + kc, &Bsm[cur ^ 1][i * 2048 + wid * 512]);
      }
    }
    const char* ab = (const char*)&Asm[cur][0];
    const char* bb = (const char*)&Bsm[cur][0];
    bf16x8 af[2][2], bfv[2][2];
    #pragma unroll
    for (int kk2 = 0; kk2 < 2; ++kk2) {
      #pragma unroll
      for (int rt = 0; rt < 2; ++rt)
        af[kk2][rt] = *(const bf16x8*)(ab + (wm * 32 + rt * 16 + n16) * 128 +
                                       (((kk2 * 4 + q4) ^ swl) << 4));
      #pragma unroll
      for (int ct = 0; ct < 2; ++ct)
        bfv[kk2][ct] = *(const bf16x8*)(bb + (wn * 32 + ct * 16 + n16) * 128 +
                                        (((kk2 * 4 + q4) ^ swl) << 4));
    }
    #pragma unroll
    for (int kk2 = 0; kk2 < 2; ++kk2)
      #pragma unroll
      for (int rt = 0; rt < 2; ++rt)
        #pragma unroll
        for (int ct = 0; ct < 2; ++ct)
          acc[rt][ct] = __builtin_amdgcn_mfma_f32_16x16x32_bf16(af[kk2][rt], bfv[kk2][ct], acc[rt][ct], 0, 0, 0);
    __syncthreads();
    cur ^= 1;
  }
  #pragma unroll
  for (int ct = 0; ct < 2; ++ct) {
    int col = n0 + wn * 32 + ct * 16 + n16;
    float bvl = bias[col];
    #pragma unroll
    for (int rt = 0; rt < 2; ++rt)
      #pragma unroll
      for (int r = 0; r < 4; ++r) {
        int row = m0 + wm * 32 + rt * 16 + q4 * 4 + r;
        outf[(size_t)row * 1024 + col] = acc[rt][ct][r] + bvl;
      }
  }
}

// ---------------------------------------------------------------------------
// K2: logits + 3x3 conv -> P = exp(conv - tile_row_max) stored in PV A-frag
// order, plus (mxt, sumP) per tile row. Kst/Ls LDS union.
// blockIdx.x == 151: Vtail suffix-scan (32 blocks) piggybacked, saves a launch.
// ---------------------------------------------------------------------------
__global__ __launch_bounds__(320) void logits_conv_k(
    const bf16* __restrict__ qh, const bf16* __restrict__ kh,
    const float* __restrict__ kq_w, const float* __restrict__ kq_b,
    bf16* __restrict__ conv_out, float* __restrict__ tstats,
    const float* __restrict__ Tsum, float* __restrict__ Vtail)
{
  const int tt = blockIdx.x;
  const int h = blockIdx.y, b = blockIdx.z;
  if (tt == 151) {           // Vtail suffix scan for (b,h)
    const int d = threadIdx.x;
    if (d < 64) {
      float* vt = Vtail + (size_t)(b * 16 + h) * 17 * 64;
      vt[16 * 64 + d] = 0.f;
      float c = 0.f;
      for (int kt = 15; kt >= 0; --kt) {
        c += Tsum[((size_t)(b * 16 + h) * 16 + kt) * 64 + d];
        vt[kt * 64 + d] = c;
      }
    }
    return;
  }
  int qt = 0, base = 0;
  while (qt < 15 && base + qt + 2 <= tt) { base += qt + 2; ++qt; }
  const int ct = tt - base;
  const int q0 = qt * 64, c0 = ct * 64;
  __shared__ __align__(16) char un[19456];      // union: Kst then Ls
  bf16* Kst = (bf16*)un;                        // [80][72] bf16, staging
  float* Ls = (float*)un;                       // [66][72] f32, logits halo
  const int tid = threadIdx.x;
  const int lane = tid & 63, wid = tid >> 6;    // 5 waves
  const int q4 = lane >> 4, n16 = lane & 15;
  const bf16* qb = qh + ((size_t)(b * 16 + h) << 16);
  const bf16* kb = kh + ((size_t)(b * 16 + h) << 16);

  // ---- A-fragments straight from global (issue first, overlap staging) ----
  const int ar = min(max(q0 - 2 + wid * 16 + n16, 0), 1023);
  bf16x8 a0 = *(const bf16x8*)(qb + ar * 64 + q4 * 8);
  bf16x8 a1 = *(const bf16x8*)(qb + ar * 64 + 32 + q4 * 8);

  // ---- coalesced K staging (contiguous 10 KB span) ----
  for (int t = tid; t < 640; t += 320) {
    int row = t >> 3, ch = t & 7;
    int br = min(max(c0 - 1 + row, 0), 1023);
    *(uint4*)(&Kst[row * 72 + ch * 8]) = *(const uint4*)(kb + br * 64 + ch * 8);
  }
  __syncthreads();

  // ---- QK^T (B-frags from LDS) ----
  f32x4 acc[5] = {};
  #pragma unroll
  for (int c5 = 0; c5 < 5; ++c5) {
    int brow = c5 * 16 + n16;
    bf16x8 b0 = *(const bf16x8*)(&Kst[brow * 72 + q4 * 8]);
    bf16x8 b1 = *(const bf16x8*)(&Kst[brow * 72 + 32 + q4 * 8]);
    acc[c5] = __builtin_amdgcn_mfma_f32_16x16x32_bf16(a0, b0, acc[c5], 0, 0, 0);
    acc[c5] = __builtin_amdgcn_mfma_f32_16x16x32_bf16(a1, b1, acc[c5], 0, 0, 0);
  }
  __syncthreads();   // Kst reads complete before Ls overwrites the union

  #pragma unroll
  for (int c5 = 0; c5 < 5; ++c5) {
    #pragma unroll
    for (int r = 0; r < 4; ++r) {
      int Lrow = wid * 16 + q4 * 4 + r;
      int Lcol = c5 * 16 + n16;
      if (Lrow < 66 && Lcol < 66) {
        int rg = q0 - 2 + Lrow;
        int cg = c0 - 1 + Lcol;
        float v = (cg >= 0 && cg <= rg) ? acc[c5][r] * 0.125f : 0.f;
        Ls[Lrow * 72 + Lcol] = v;
      }
    }
  }
  __syncthreads();

  if (tid < 256) {
    float w9[9];
    #pragma unroll
    for (int i = 0; i < 9; ++i) w9[i] = kq_w[h * 9 + i];
    const float bb = kq_b[h];
    const size_t tplane = (size_t)(b * 16 + h) * 151 + base + ct;
    bf16* tb = conv_out + tplane * 4096;
    float2* st = (float2*)tstats + tplane * 64;

    const int r = tid >> 2, qr = tid & 3;   // output row, 16-col quarter
    float4 R0[5], R1[5], R2[5];
    const float* L0 = &Ls[r * 72 + qr * 16];
    #pragma unroll
    for (int i = 0; i < 5; ++i) {
      R0[i] = *(const float4*)(L0 + i * 4);
      R1[i] = *(const float4*)(L0 + 72 + i * 4);
      R2[i] = *(const float4*)(L0 + 144 + i * 4);
    }
    const float* f0 = (const float*)R0;
    const float* f1 = (const float*)R1;
    const float* f2 = (const float*)R2;
    float o[16];
    #pragma unroll
    for (int jj = 0; jj < 16; ++jj)
      o[jj] = bb + w9[0]*f0[jj] + w9[1]*f0[jj+1] + w9[2]*f0[jj+2]
                 + w9[3]*f1[jj] + w9[4]*f1[jj+1] + w9[5]*f1[jj+2]
                 + w9[6]*f2[jj] + w9[7]*f2[jj+1] + w9[8]*f2[jj+2];
    float mx = o[0];
    #pragma unroll
    for (int jj = 1; jj < 16; ++jj) mx = fmaxf(mx, o[jj]);
    mx = fmaxf(mx, __shfl_xor(mx, 1));
    mx = fmaxf(mx, __shfl_xor(mx, 2));
    unsigned int p[8];
    #pragma unroll
    for (int jj = 0; jj < 8; ++jj)
      p[jj] = cvt_pk_bf16(__expf(o[2*jj] - mx), __expf(o[2*jj+1] - mx));
    // store in PV A-frag order: [sr][kk][q4*16+n16][8]
    const int kk = qr >> 1, q4b = (qr & 1) * 2, sr = r >> 4, n16r = r & 15;
    *(uint4*)(tb + (sr * 2 + kk) * 512 + (q4b * 16 + n16r) * 8)       = *(const uint4*)&p[0];
    *(uint4*)(tb + (sr * 2 + kk) * 512 + ((q4b + 1) * 16 + n16r) * 8) = *(const uint4*)&p[4];
    float s = 0.f;
    #pragma unroll
    for (int jj = 0; jj < 8; ++jj) s += bf_lo(p[jj]) + bf_hi(p[jj]);
    s += __shfl_xor(s, 1);
    s += __shfl_xor(s, 2);
    if (qr == 0) st[r] = make_float2(mx, s);
  }
}

// ---------------------------------------------------------------------------
// K3b: PV from fragment-ordered P and V2, with per-row (m, 1/l) stats
// computed INLINE: each block owns exactly its 16 rows x 2 heads.
// ---------------------------------------------------------------------------
__global__ __launch_bounds__(256) void pv_k(
    const bf16* __restrict__ conv_out, const bf16* __restrict__ V2,
    const float* __restrict__ tstats, const float* __restrict__ Vtail,
    const float* __restrict__ mix_w, const float* __restrict__ mix_b,
    const float* __restrict__ kq_b,
    const float* __restrict__ dyt_alpha, const float* __restrict__ dyt_w,
    const float* __restrict__ dyt_b, const float* __restrict__ depth_scale,
    bf16* __restrict__ out_attn)
{
  const int qt16 = blockIdx.x, g = blockIdx.y, b = blockIdx.z;
  const int qt = qt16 >> 2;
  const int nkt = min(qt + 2, 16);
  const int Tc = 1024 - (nkt << 6);
  const int tid = threadIdx.x, lane = tid & 63, wid = tid >> 6;
  const int q4 = lane >> 4, n16 = lane & 15;
  const int oo = wid >> 1, kh = wid & 1;
  const int h0 = 2 * g, ho = h0 + oo;
  const int sr = qt16 & 3, strow = sr * 16;
  const size_t tbase = (size_t)(qt * (qt + 3) / 2);

  // ---- inline combine: per-row (m, 1/l) for this block's 16 rows x 2 heads
  __shared__ float2 rsS[2][16];
  if (tid < 32) {
    const int hh = tid >> 4, rw = tid & 15;
    const float2* tsp = (const float2*)tstats +
        ((size_t)(b * 16 + h0 + hh) * 151 + tbase) * 64 + strow + rw;
    const float kb2 = kq_b[h0 + hh];
    float mx = (Tc > 0) ? kb2 : -3.0e38f;
    for (int kt = 0; kt < nkt; ++kt) mx = fmaxf(mx, tsp[(size_t)kt * 64].x);
    float s = (float)Tc * __expf(kb2 - mx);
    for (int kt = 0; kt < nkt; ++kt) {
      float2 v = tsp[(size_t)kt * 64];
      s += v.y * __expf(v.x - mx);
    }
    rsS[hh][rw] = make_float2(mx, 1.f / s);
  }
  __syncthreads();

  const float2 r0 = rsS[0][n16];
  const float2 r1 = rsS[1][n16];
  const float m0 = r0.x, m1 = r1.x;
  const float mwa = mix_w[ho * 2 + 0], mwb = mix_w[ho * 2 + 1];
  const float wa = mwa * r0.y, wb = mwb * r1.y;   // mw * rinv

  const bf16* pb0 = conv_out +
      ((size_t)(b * 16 + h0) * 151 + tbase) * 4096 + sr * 1024 + lane * 8;
  const bf16* pb1 = pb0 + (size_t)151 * 4096;
  const float2* ts0 = (const float2*)tstats +
      ((size_t)(b * 16 + h0) * 151 + tbase) * 64 + strow + n16;
  const float2* ts1 = ts0 + (size_t)151 * 64;
  const bf16* vb = V2 + ((size_t)(b * 16 + ho) << 16) + lane * 8;

  const int niter = (nkt - kh + 1) >> 1;
  float wk0[8], wk1[8];
  #pragma unroll
  for (int i = 0; i < 8; ++i) {
    int ktc = (i < niter) ? (kh + 2 * i) : 0;
    wk0[i] = wa * __expf(ts0[(size_t)ktc * 64].x - m0);
    wk1[i] = wb * __expf(ts1[(size_t)ktc * 64].x - m1);
  }

  f32x4 acc[4] = {};
  int ii = 0;
  for (int kt = kh; kt < nkt; kt += 2, ++ii) {
    uint4 u0[2], u1[2];
    #pragma unroll
    for (int kk = 0; kk < 2; ++kk) {
      u0[kk] = *(const uint4*)(pb0 + (size_t)kt * 4096 + kk * 512);
      u1[kk] = *(const uint4*)(pb1 + (size_t)kt * 4096 + kk * 512);
    }
    bf16x8 bv[2][4];
    #pragma unroll
    for (int kk = 0; kk < 2; ++kk)
      #pragma unroll
      for (int ctt = 0; ctt < 4; ++ctt)
        bv[kk][ctt] = *(const bf16x8*)(vb + (size_t)kt * 4096 + kk * 2048 + ctt * 512);
    const float w0 = wk0[ii], w1 = wk1[ii];
    #pragma unroll
    for (int kk = 0; kk < 2; ++kk) {
      bf16x8 af;
      const unsigned int* a0p = (const unsigned int*)&u0[kk];
      const unsigned int* a1p = (const unsigned int*)&u1[kk];
      #pragma unroll
      for (int i2 = 0; i2 < 4; ++i2) {
        float a0 = w0 * bf_lo(a0p[i2]) + w1 * bf_lo(a1p[i2]);
        float a1 = w0 * bf_hi(a0p[i2]) + w1 * bf_hi(a1p[i2]);
        ((unsigned int*)&af)[i2] = cvt_pk_bf16(a0, a1);
      }
      #pragma unroll
      for (int ctt = 0; ctt < 4; ++ctt)
        acc[ctt] = __builtin_amdgcn_mfma_f32_16x16x32_bf16(af, bv[kk][ctt], acc[ctt], 0, 0, 0);
    }
  }

  __shared__ float Pp[2][16][64];
  if (kh == 1) {
    #pragma unroll
    for (int ctt = 0; ctt < 4; ++ctt)
      #pragma unroll
      for (int r = 0; r < 4; ++r)
        Pp[oo][q4 * 4 + r][ctt * 16 + n16] = acc[ctt][r];
  }
  __syncthreads();
  if (kh == 1) return;
  #pragma unroll
  for (int ctt = 0; ctt < 4; ++ctt)
    #pragma unroll
    for (int r = 0; r < 4; ++r)
      acc[ctt][r] += Pp[oo][q4 * 4 + r][ctt * 16 + n16];

  const float kqb0 = kq_b[h0], kqb1 = kq_b[h0 + 1];
  float tw[4];
  #pragma unroll
  for (int r = 0; r < 4; ++r) {
    float2 s0 = rsS[0][q4 * 4 + r];
    float2 s1 = rsS[1][q4 * 4 + r];
    tw[r] = (Tc > 0) ? (mwa * s0.y * __expf(kqb0 - s0.x) +
                        mwb * s1.y * __expf(kqb1 - s1.x)) : 0.f;
  }
  const float mb = mix_b[ho];
  const float alpha = dyt_alpha[0], dsc = depth_scale[0];
  const float* vt = Vtail + (size_t)(b * 16 + ho) * 17 * 64;
  #pragma unroll
  for (int ctt = 0; ctt < 4; ++ctt) {
    int d = ctt * 16 + n16;
    float vtn = vt[(size_t)nkt * 64 + d];
    float vt0 = vt[d];
    float wgt = dyt_w[d], bds = dyt_b[d];
    #pragma unroll
    for (int r = 0; r < 4; ++r) {
      float v = acc[ctt][r] + tw[r] * vtn + mb * vt0;
      float e = __expf(2.f * alpha * v);
      float th = 1.f - 2.f / (e + 1.f);
      float y = (th * wgt + bds) * dsc;
      int qr = qt16 * 16 + q4 * 4 + r;
      out_attn[(((size_t)(b * 1024 + qr)) << 10) + ho * 64 + d] = (bf16)y;
    }
  }
}

// ---------------------------------------------------------------------------
extern "C" void kernel_launch(void* const* d_in, const int* in_sizes, int n_in,
                              void* d_out, int out_size, void* d_ws, size_t ws_size,
                              hipStream_t stream) {
  const float* Q    = (const float*)d_in[0];
  const float* Kx   = (const float*)d_in[1];
  const float* V    = (const float*)d_in[2];
  const float* Wq   = (const float*)d_in[3];
  const float* bq   = (const float*)d_in[4];
  const float* Wk   = (const float*)d_in[5];
  const float* bk   = (const float*)d_in[6];
  const float* Wv   = (const float*)d_in[7];
  const float* bv   = (const float*)d_in[8];
  const float* Wo   = (const float*)d_in[9];
  const float* bo   = (const float*)d_in[10];
  const float* kq_w = (const float*)d_in[11];
  const float* kq_b = (const float*)d_in[12];
  const float* mixw = (const float*)d_in[13];
  const float* mixb = (const float*)d_in[14];
  const float* dyta = (const float*)d_in[15];
  const float* dytw = (const float*)d_in[16];
  const float* dytb = (const float*)d_in[17];
  const float* dsc  = (const float*)d_in[18];

  char* ws = (char*)d_ws;
  bf16* qh     = (bf16*)(ws);                              // 4 MB (kh, V2 follow)
  float* tstat = (float*)(ws + (size_t)(12 << 20));        // 2.42 MB (alive thru pv)
  float* Vtail = (float*)(ws + (size_t)(16 << 20));        // 136 KB
  float* Tsum  = (float*)(ws + (size_t)(16 << 20) + (256 << 10)); // 128 KB
  bf16* WtT    = (bf16*)(ws + (size_t)(17 << 20));         // 8 MB (4 planes x 2MB)
  bf16* oat    = (bf16*)(ws + (size_t)(17 << 20));         // 4 MB, aliases Wq/Wk planes
  bf16* conv   = (bf16*)(ws + (size_t)(25 << 20));         // 39.58 MB (P2 tiles)
  bf16* Ab     = (bf16*)(ws + (size_t)(25 << 20));         // 12 MB, aliases conv (dead then)
  bf16* kh     = qh + ((size_t)1 << 21);
  bf16* V2     = qh + ((size_t)2 << 21);

  prep_k<<<dim3(4096), 256, 0, stream>>>(Wq, Wk, Wv, Wo, Q, Kx, V, WtT, Ab);
  proj_gemm_k<<<dim3(256, 1, 3), 256, 0, stream>>>(Ab, WtT, bq, bk, bv, qh, Tsum);
  logits_conv_k<<<dim3(152, 16, 2), 320, 0, stream>>>(qh, kh, kq_w, kq_b, conv, tstat,
                                                      Tsum, Vtail);
  pv_k<<<dim3(64, 8, 2), 256, 0, stream>>>(conv, V2, tstat, Vtail, mixw, mixb, kq_b,
                                           dyta, dytw, dytb, dsc, oat);
  out_gemm_k<<<dim3(512), 256, 0, stream>>>(oat, WtT + ((size_t)3 << 20), bo, (float*)d_out);
}